// Round 8
// baseline (245.968 us; speedup 1.0000x reference)
//
#include <hip/hip_runtime.h>
#include <cstdint>

typedef __attribute__((ext_vector_type(8)))  short bf16x8;   // 8 x bf16 (4 VGPR)
typedef __attribute__((ext_vector_type(16))) float f32x16;   // MFMA 32x32 acc
typedef __attribute__((ext_vector_type(4)))  int   i32x4;

__device__ __forceinline__ unsigned short f2bf(float x) {    // RNE fp32->bf16
  unsigned u = __float_as_uint(x);
  u += 0x7fffu + ((u >> 16) & 1u);
  return (unsigned short)(u >> 16);
}
__device__ __forceinline__ unsigned pk2bf(float lo, float hi) {
#if defined(__has_builtin)
#if __has_builtin(__builtin_amdgcn_cvt_pk_bf16_f32)
  auto v = __builtin_amdgcn_cvt_pk_bf16_f32(lo, hi);
  unsigned u; __builtin_memcpy(&u, &v, 4); return u;
#else
  return ((unsigned)f2bf(hi) << 16) | (unsigned)f2bf(lo);
#endif
#else
  return ((unsigned)f2bf(hi) << 16) | (unsigned)f2bf(lo);
#endif
}
__device__ __forceinline__ float silu_f(float v) {
  return v * __builtin_amdgcn_rcpf(1.0f + __expf(-v));
}

// half-exchange without the LDS pipe: lanes 0-31 receive A from lane+32,
// lanes 32-63 receive B from lane-32  (== __shfl_xor(q ? A : B, 32)).
__device__ __forceinline__ float xchg32(float A, float B, int q) {
#if defined(__has_builtin)
#if __has_builtin(__builtin_amdgcn_permlane32_swap)
  auto r = __builtin_amdgcn_permlane32_swap(__float_as_uint(A), __float_as_uint(B),
                                            false, false);
  return __uint_as_float(q ? r[0] : r[1]);
#else
  return __shfl_xor(q ? A : B, 32);
#endif
#else
  return __shfl_xor(q ? A : B, 32);
#endif
}

// ---- on-the-fly B-frag load from raw W (fp32, row-major KxN, N=256):
// lane's 8 bf16 = W[kbase..kbase+7][col] * 1/3. Replaces the pack_kernel
// (same *0.33333334f + cvt_pk rounding -> numerically identical), kills the
// second kernel launch. W is L2-resident (<=256KB/layer); lanes c=0..31 read
// 128B-contiguous segments per j -> 2 segments/instr, acceptable coalescing.
__device__ __forceinline__ bf16x8 loadW3(const float* __restrict__ Wp,
                                         const int kbase, const int col) {
  float f[8];
#pragma unroll
  for (int j = 0; j < 8; ++j) f[j] = Wp[(kbase + j) * 256 + col] * 0.33333334f;
  i32x4 v = { (int)pk2bf(f[0], f[1]), (int)pk2bf(f[2], f[3]),
              (int)pk2bf(f[4], f[5]), (int)pk2bf(f[6], f[7]) };
  return __builtin_bit_cast(bf16x8, v);
}
__device__ __forceinline__ bf16x8 loadW3m(const float* __restrict__ Wp,
                                          const int kbase, const int col, const int kmax) {
  float f[8];
#pragma unroll
  for (int j = 0; j < 8; ++j) {
    const int k = kbase + j;
    f[j] = (k < kmax) ? Wp[k * 256 + col] * 0.33333334f : 0.f;   // OOB-safe tail
  }
  i32x4 v = { (int)pk2bf(f[0], f[1]), (int)pk2bf(f[2], f[3]),
              (int)pk2bf(f[4], f[5]), (int)pk2bf(f[6], f[7]) };
  return __builtin_bit_cast(bf16x8, v);
}

// ======================================================================
// Wave w owns ALL 256 nodes x cols [32w,32w+32). Node->A-row permutation puts
// 16 CONSECUTIVE nodes in each lane's acc regs: node 32nt + 16q + r.
// s~[n] = (h W/3)[n] + bias/3 (bias via acc init) => y[n] = silu(s~[n-1]+s~[n]+s~[n+1]).
// L0 temb-fold: tW = temb @ W0/3 once per wave (9 MFMAs, broadcast A); L0 acc
// init = tW + b0/3; per-node L0 GEMM K=16 (coords+pe, 1 kt).
// 4 subs of 2 tiles, ping-pong acc, kloop interleaved 1:1 with prev-sub epilogue,
// DEPTH-2 A-frag prefetch (covers ~120cy LDS latency; kt&1 static ping-pong).
// Boundary exchange via v_permlane32_swap. h' stores via v_cvt_pk_bf16_f32.
// h[256][256] bf16 in 128KB LDS, 16B-slot XOR swizzle (slot ^= row&31).
// B slice resident in 64 VGPRs, loaded straight from W (no pack kernel).
// ======================================================================

// one epilogue PAIR p (values r=2(p&7), +1 of tile t=p>>3); mid-sum shared
template <int ELAYER, bool DF, bool DL>
__device__ __forceinline__ void epi_pair(
    const int p, const f32x16* accEpi, const int q,
    const float recvI0, const float recvI1, const float recvX,
    const float extP, const float extN,
    const int epiSub, unsigned short* __restrict__ hbuf,
    const int* rowAddr, float& psum) {
  const int t = p >> 3, rp = (p & 7) * 2;
  const float mid = accEpi[t][rp] + accEpi[t][rp + 1];
  float prev, next;
  if (rp > 0) prev = accEpi[t][rp - 1];
  else        prev = q ? (t ? recvI1 : recvI0) : (t ? recvX : extP);
  if (rp < 14) next = accEpi[t][rp + 2];
  else         next = q ? (t ? extN : recvX) : (t ? recvI1 : recvI0);
  const float y0 = silu_f(prev + mid);
  const float y1 = silu_f(mid + next);
  const bool c0 = !(DF && t == 0 && rp == 0 && q == 0);
  const bool c1 = !(DL && t == 1 && rp == 14 && q == 1);
  if constexpr (ELAYER == 2) {
    if (c0) psum += y0;
    if (c1) psum += y1;
  } else {
    const unsigned u = pk2bf(y0, y1);
    char* bp = (char*)hbuf + (2 * epiSub + t) * 16384;
    if (c0) *(unsigned short*)(bp + rowAddr[rp])     = (unsigned short)u;
    if (c1) *(unsigned short*)(bp + rowAddr[rp + 1]) = (unsigned short)(u >> 16);
  }
}

// fused block: kloop over 2 tiles of readSub (acc init = bias-ish scalar),
// depth-2 A prefetch, interleaved with epilogue pairs of epiSub (prev sub).
template <int KT, int ELAYER, bool DOEPI, bool DF, bool DL>
__device__ __forceinline__ void fblock(
    unsigned short* __restrict__ hbuf, const int readSub, const int epiSub,
    const bf16x8* Bf, const int q, const int c, const float bias3,
    f32x16* accOut, const f32x16* accEpi,
    const float extP, const float extN,
    const int* rowAddr, float& psum) {
  float recvI0 = 0.f, recvI1 = 0.f, recvX = 0.f;
  if constexpr (DOEPI) {
    recvI0 = xchg32(accEpi[0][0],  accEpi[0][15], q);
    recvI1 = xchg32(accEpi[1][0],  accEpi[1][15], q);
    recvX  = xchg32(accEpi[0][15], accEpi[1][0],  q);
  }
#pragma unroll
  for (int t2 = 0; t2 < 2; ++t2)
#pragma unroll
    for (int j = 0; j < 16; ++j) accOut[t2][j] = bias3;
  const unsigned short* rb = hbuf + readSub * 16384 + c * 256;
  bf16x8 pa[2], pb[2];                           // depth-2 ping-pong prefetch
  pa[0] = *(const bf16x8*)(rb + ((q ^ c) * 8));
  pb[0] = *(const bf16x8*)(rb + ((q ^ c) * 8) + 8192);
  if (KT > 1) {
    pa[1] = *(const bf16x8*)(rb + (((2 + q) ^ c) * 8));
    pb[1] = *(const bf16x8*)(rb + (((2 + q) ^ c) * 8) + 8192);
  }
#pragma unroll
  for (int kt = 0; kt < KT; ++kt) {
    const bf16x8 u0 = pa[kt & 1], u1 = pb[kt & 1];
    if (kt + 2 < KT) {
      const unsigned short* nb = rb + (((2 * (kt + 2) + q) ^ c) * 8);
      pa[kt & 1] = *(const bf16x8*)(nb);
      pb[kt & 1] = *(const bf16x8*)(nb + 8192);
    }
    accOut[0] = __builtin_amdgcn_mfma_f32_32x32x16_bf16(u0, Bf[kt], accOut[0], 0, 0, 0);
    accOut[1] = __builtin_amdgcn_mfma_f32_32x32x16_bf16(u1, Bf[kt], accOut[1], 0, 0, 0);
    if constexpr (DOEPI) {
#pragma unroll
      for (int p = (kt * 16) / KT; p < ((kt + 1) * 16) / KT; ++p)
        epi_pair<ELAYER, DF, DL>(p, accEpi, q, recvI0, recvI1, recvX, extP, extN,
                                 epiSub, hbuf, rowAddr, psum);
    }
  }
}

template <int ELAYER>
__device__ __forceinline__ void epi_only(
    const f32x16* accEpi, const int q, const float extP, const float extN,
    const int epiSub, unsigned short* __restrict__ hbuf,
    const int* rowAddr, float& psum) {
  const float recvI0 = xchg32(accEpi[0][0],  accEpi[0][15], q);
  const float recvI1 = xchg32(accEpi[1][0],  accEpi[1][15], q);
  const float recvX  = xchg32(accEpi[0][15], accEpi[1][0],  q);
#pragma unroll
  for (int p = 0; p < 16; ++p)
    epi_pair<ELAYER, false, false>(p, accEpi, q, recvI0, recvI1, recvX, extP, extN,
                                   epiSub, hbuf, rowAddr, psum);
}

// node 64e+63 (q1 lanes): prev/cur in accEpi[1][14..15], next = new sub's node 64e+64
template <int ELAYER>
__device__ __forceinline__ void defer_last(
    const f32x16* accEpi, const float accNew00, const int epiSub,
    const int q, unsigned short* __restrict__ hbuf,
    const int* rowAddr, float& psum) {
  const float recv = xchg32(0.f, accNew00, q);   // q1 <- s~[64e+64]
  const float y = silu_f(accEpi[1][14] + accEpi[1][15] + recv);
  if (q) {
    if constexpr (ELAYER == 2) psum += y;
    else *(unsigned short*)((char*)hbuf + (2 * epiSub + 1) * 16384 + rowAddr[15]) = f2bf(y);
  }
}

// node 0 (q0 lanes): prev = s~[255], cur/next = saved s~[0], s~[1]
template <int ELAYER>
__device__ __forceinline__ void fix_node0(
    const float s255src, const float sv0, const float sv1,
    const int q, unsigned short* __restrict__ hbuf,
    const int* rowAddr, float& psum) {
  const float recv = xchg32(s255src, 0.f, q);    // q0 <- s~[255]
  const float y = silu_f(recv + sv0 + sv1);
  if (!q) {
    if constexpr (ELAYER == 2) psum += y;
    else *(unsigned short*)((char*)hbuf + rowAddr[0]) = f2bf(y);
  }
}

// ---------------- main fused kernel: 1 block = 1 graph, 8 waves x 32 cols ----------
__global__ __launch_bounds__(512, 1) void poly_kernel(
    const float* __restrict__ x, const float* __restrict__ t,
    const float* __restrict__ tw, const float* __restrict__ tb,
    const float* __restrict__ W0, const float* __restrict__ B0,
    const float* __restrict__ W1, const float* __restrict__ B1,
    const float* __restrict__ W2, const float* __restrict__ B2,
    float* __restrict__ out) {
  __shared__ __align__(16) unsigned short hbuf[65536];  // 128 KiB: h[row][256] bf16, swizzled
  __shared__ __align__(16) unsigned short tmpl[160];    // h0 row template (temb + pads)

  const int tid = threadIdx.x;
  const int w = tid >> 6, lane = tid & 63, q = lane >> 5, c = lane & 31;
  const int b = blockIdx.x;
  const int col = w * 32 + c;                    // this lane's output column

  // ---- fused time MLP: temb = silu(sinemb(t[b]) @ tw + tb) ----
  {
    float* scr = (float*)hbuf;        // reuse h as f32 scratch (overwritten later)
    if (tid < 128) {
      const float tv = t[b];
      const int i = tid & 63;
      const float f = expf(-0.14619588396823767f * (float)i);  // log(1e4)/63
      const float ang = tv * f;
      scr[tid] = (tid < 64) ? sinf(ang) : cosf(ang);
    }
    __syncthreads();
    {
      const int j = tid & 127, p = tid >> 7;   // 4-way k-split over the block
      float a = 0.f;
#pragma unroll 8
      for (int kk = 0; kk < 32; ++kk) a += scr[p * 32 + kk] * tw[(p * 32 + kk) * 128 + j];
      scr[128 + tid] = a;
    }
    __syncthreads();
    if (tid < 128) {
      const float a = tb[tid] + scr[128 + tid] + scr[256 + tid] + scr[384 + tid] + scr[512 + tid];
      tmpl[6 + tid] = f2bf(silu_f(a));
      if (tid < 6)  tmpl[tid] = 0;
      if (tid < 26) tmpl[134 + tid] = 0;   // pad k 134..159 = 0
    }
    __syncthreads();
  }

  // ---- L0 B slice straight from W0/3 (K padded 134->144; kt=8 masked) ----
  bf16x8 Bf[16];
#pragma unroll
  for (int kt = 0; kt < 8; ++kt) Bf[kt] = loadW3(W0, kt * 16 + 8 * q, col);
  Bf[8] = loadW3m(W0, 128 + 8 * q, col, 134);
  const float b30 = B0[col] * 0.33333334f;
  const float b31 = B1[col] * 0.33333334f;
  const float b32 = B2[col] * 0.33333334f;

  // ---- tW fold: node-invariant part of L0 (temb @ W0/3), once per wave ----
  // A rows all = tmpl (zeros in k0..5) -> every C element = tW[col]; take C[0].
  float initL0;
  {
    f32x16 Ct;
#pragma unroll
    for (int j = 0; j < 16; ++j) Ct[j] = 0.f;
#pragma unroll
    for (int kt = 0; kt < 9; ++kt) {
      const bf16x8 at = *(const bf16x8*)(tmpl + kt * 16 + q * 8);
      Ct = __builtin_amdgcn_mfma_f32_32x32x16_bf16(at, Bf[kt], Ct, 0, 0, 0);
    }
    initL0 = Ct[0] + b30;
  }

  // ---- build h0 (features only): slots 0,1 per node = [xy, pe, 0-pad] ----
  {
    const int node = tid >> 1, sl = tid & 1;
    i32x4 d = {0, 0, 0, 0};
    if (sl == 0) {
      const float2 xy = ((const float2*)x)[b * 256 + node];
      const float th = 0.024543692605870074f * (float)node;   // 2*pi/256
      d.x = (int)pk2bf(xy.x, xy.y);
      d.y = (int)pk2bf(sinf(th), cosf(th));
      d.z = (int)pk2bf(sinf(2.f * th), cosf(2.f * th));
    }
    const int m = (node & 3) + 8 * ((node >> 2) & 3) + 4 * ((node >> 4) & 1);
    const int R = (node & ~31) | m;            // permuted LDS row
    *(i32x4*)(hbuf + R * 256 + ((sl ^ m) * 8)) = d;
  }

  // per-lane h'-write byte addresses (row within tile; r compile-time)
  int rowAddr[16];
  const int slotW = 4 * w + (c >> 3), offW = (c & 7) * 2;    // k-index = col
#pragma unroll
  for (int r = 0; r < 16; ++r) {
    const int row = (r & 3) + 8 * (r >> 2) + 4 * q;
    rowAddr[r] = row * 512 + ((slotW ^ row) * 16) + offW;
  }
  __syncthreads();   // h0 ready

  f32x16 accA[2], accB[2];
  float psum = 0.f, sv0, sv1, extP, extN;

  // ================= L0 (K=16: coords+pe; temb folded into initL0) =================
  fblock<1, 0, false, false, false>(hbuf, 0, 0, Bf, q, c, initL0, accA, accA, 0.f, 0.f, rowAddr, psum);
  sv0 = accA[0][0]; sv1 = accA[0][1];                       // s~[0], s~[1] (q0)
  __syncthreads();
  fblock<1, 0, true, true, true>(hbuf, 1, 0, Bf, q, c, initL0, accB, accA, 0.f, 0.f, rowAddr, psum);
  defer_last<0>(accA, accB[0][0], 0, q, hbuf, rowAddr, psum);       // node 63
  extP = xchg32(accA[1][15], 0.f, q);                               // s~[63] -> q0
  __syncthreads();
  fblock<1, 0, true, false, true>(hbuf, 2, 1, Bf, q, c, initL0, accA, accB, extP, 0.f, rowAddr, psum);
  defer_last<0>(accB, accA[0][0], 1, q, hbuf, rowAddr, psum);       // node 127
  extP = xchg32(accB[1][15], 0.f, q);                               // s~[127]
  __syncthreads();
  fblock<1, 0, true, false, true>(hbuf, 3, 2, Bf, q, c, initL0, accB, accA, extP, 0.f, rowAddr, psum);
  // issue next-layer Bf loads FIRST (VMEM latency hides under fixup VALU + barrier)
#pragma unroll
  for (int kt = 0; kt < 16; ++kt) Bf[kt] = loadW3(W1, kt * 16 + 8 * q, col);
  defer_last<0>(accA, accB[0][0], 2, q, hbuf, rowAddr, psum);       // node 191
  fix_node0<0>(accB[1][15], sv0, sv1, q, hbuf, rowAddr, psum);      // node 0
  extP = xchg32(accA[1][15], 0.f, q);                               // s~[191]
  extN = xchg32(0.f, sv0, q);                                       // s~[0] -> q1
  __syncthreads();

  // ================= L1 =================
  fblock<16, 0, true, false, false>(hbuf, 0, 3, Bf, q, c, b31, accA, accB, extP, extN, rowAddr, psum);
  sv0 = accA[0][0]; sv1 = accA[0][1];
  __syncthreads();
  fblock<16, 1, true, true, true>(hbuf, 1, 0, Bf, q, c, b31, accB, accA, 0.f, 0.f, rowAddr, psum);
  defer_last<1>(accA, accB[0][0], 0, q, hbuf, rowAddr, psum);
  extP = xchg32(accA[1][15], 0.f, q);
  __syncthreads();
  fblock<16, 1, true, false, true>(hbuf, 2, 1, Bf, q, c, b31, accA, accB, extP, 0.f, rowAddr, psum);
  defer_last<1>(accB, accA[0][0], 1, q, hbuf, rowAddr, psum);
  extP = xchg32(accB[1][15], 0.f, q);
  __syncthreads();
  fblock<16, 1, true, false, true>(hbuf, 3, 2, Bf, q, c, b31, accB, accA, extP, 0.f, rowAddr, psum);
#pragma unroll
  for (int kt = 0; kt < 16; ++kt) Bf[kt] = loadW3(W2, kt * 16 + 8 * q, col);
  defer_last<1>(accA, accB[0][0], 2, q, hbuf, rowAddr, psum);
  fix_node0<1>(accB[1][15], sv0, sv1, q, hbuf, rowAddr, psum);
  extP = xchg32(accA[1][15], 0.f, q);
  extN = xchg32(0.f, sv0, q);
  __syncthreads();

  // ================= L2 (pool only; no LDS writes -> fewer barriers) =================
  fblock<16, 1, true, false, false>(hbuf, 0, 3, Bf, q, c, b32, accA, accB, extP, extN, rowAddr, psum);
  sv0 = accA[0][0]; sv1 = accA[0][1];
  __syncthreads();                              // epi(s3,L1) wrote rows 192..255
  fblock<16, 2, true, true, true>(hbuf, 1, 0, Bf, q, c, b32, accB, accA, 0.f, 0.f, rowAddr, psum);
  defer_last<2>(accA, accB[0][0], 0, q, hbuf, rowAddr, psum);
  extP = xchg32(accA[1][15], 0.f, q);
  fblock<16, 2, true, false, true>(hbuf, 2, 1, Bf, q, c, b32, accA, accB, extP, 0.f, rowAddr, psum);
  defer_last<2>(accB, accA[0][0], 1, q, hbuf, rowAddr, psum);
  extP = xchg32(accB[1][15], 0.f, q);
  fblock<16, 2, true, false, true>(hbuf, 3, 2, Bf, q, c, b32, accB, accA, extP, 0.f, rowAddr, psum);
  defer_last<2>(accA, accB[0][0], 2, q, hbuf, rowAddr, psum);
  fix_node0<2>(accB[1][15], sv0, sv1, q, hbuf, rowAddr, psum);
  extP = xchg32(accA[1][15], 0.f, q);
  extN = xchg32(0.f, sv0, q);
  epi_only<2>(accB, q, extP, extN, 3, hbuf, rowAddr, psum);

  const float s2 = psum + xchg32(psum, psum, q);
  if (q == 0) out[b * 256 + col] = s2 * (1.0f / 256.0f);
}

// ---------------- launch: single fused kernel (pack merged) ----------------
extern "C" void kernel_launch(void* const* d_in, const int* in_sizes, int n_in,
                              void* d_out, int out_size, void* d_ws, size_t ws_size,
                              hipStream_t stream) {
  const float* x  = (const float*)d_in[0];
  const float* t  = (const float*)d_in[1];
  const float* tw = (const float*)d_in[2];
  const float* tb = (const float*)d_in[3];
  const float* W0 = (const float*)d_in[4];
  const float* b0 = (const float*)d_in[5];
  const float* W1 = (const float*)d_in[6];
  const float* b1 = (const float*)d_in[7];
  const float* W2 = (const float*)d_in[8];
  const float* b2 = (const float*)d_in[9];
  float* out = (float*)d_out;

  poly_kernel<<<1024, 512, 0, stream>>>(x, t, tw, tb, W0, b0, W1, b1, W2, b2, out);
}

// Round 9
// 175.856 us; speedup vs baseline: 1.3987x; 1.3987x over previous
//
#include <hip/hip_runtime.h>
#include <cstdint>

typedef __attribute__((ext_vector_type(8)))  short bf16x8;   // 8 x bf16 (4 VGPR)
typedef __attribute__((ext_vector_type(16))) float f32x16;   // MFMA 32x32 acc
typedef __attribute__((ext_vector_type(4)))  int   i32x4;

__device__ __forceinline__ unsigned short f2bf(float x) {    // RNE fp32->bf16
  unsigned u = __float_as_uint(x);
  u += 0x7fffu + ((u >> 16) & 1u);
  return (unsigned short)(u >> 16);
}
__device__ __forceinline__ unsigned pk2bf(float lo, float hi) {
#if defined(__has_builtin)
#if __has_builtin(__builtin_amdgcn_cvt_pk_bf16_f32)
  auto v = __builtin_amdgcn_cvt_pk_bf16_f32(lo, hi);
  unsigned u; __builtin_memcpy(&u, &v, 4); return u;
#else
  return ((unsigned)f2bf(hi) << 16) | (unsigned)f2bf(lo);
#endif
#else
  return ((unsigned)f2bf(hi) << 16) | (unsigned)f2bf(lo);
#endif
}
__device__ __forceinline__ float silu_f(float v) {
  return v * __builtin_amdgcn_rcpf(1.0f + __expf(-v));
}

// half-exchange without the LDS pipe: lanes 0-31 receive A from lane+32,
// lanes 32-63 receive B from lane-32  (== __shfl_xor(q ? A : B, 32)).
__device__ __forceinline__ float xchg32(float A, float B, int q) {
#if defined(__has_builtin)
#if __has_builtin(__builtin_amdgcn_permlane32_swap)
  auto r = __builtin_amdgcn_permlane32_swap(__float_as_uint(A), __float_as_uint(B),
                                            false, false);
  return __uint_as_float(q ? r[0] : r[1]);
#else
  return __shfl_xor(q ? A : B, 32);
#endif
#else
  return __shfl_xor(q ? A : B, 32);
#endif
}

// ---- pack W/3 into MFMA B-frag order via LDS transpose (coalesced R+W).
// 1/3 aggregation factor folded into the weights; bias folded into acc init.
// dest layout: [layer][g(64 cols)][t(32-col tile)][kt][lane][8], K0 padded 134->144.
__global__ void pack_kernel(const float* __restrict__ W0, const float* __restrict__ W1,
                            const float* __restrict__ W2,
                            unsigned short* __restrict__ packW) {
  __shared__ float ldsF[16][257];
  const int s = blockIdx.x, tid = threadIdx.x;
  const float* W; int KT, kmax, base, kt;
  if (s < 9)       { W = W0; KT = 9;  kmax = 134; base = 0;      kt = s; }
  else if (s < 25) { W = W1; KT = 16; kmax = 256; base = 36864;  kt = s - 9; }
  else             { W = W2; KT = 16; kmax = 256; base = 102400; kt = s - 25; }
  const int k0 = kt * 16;
#pragma unroll
  for (int i = 0; i < 8; ++i) {                 // 512 thr x 8 = 16 x 256 floats
    const int idx = i * 512 + tid;
    const int kl = idx >> 8, col = idx & 255;
    const int kg = k0 + kl;
    ldsF[kl][col] = (kg < kmax) ? W[kg * 256 + col] * 0.33333334f : 0.0f;
  }
  __syncthreads();
  const int g = tid >> 7, t = (tid >> 6) & 1, lane = tid & 63;
  const int col = g * 64 + t * 32 + (lane & 31);
  const int kb = 8 * (lane >> 5);
  unsigned u0 = pk2bf(ldsF[kb + 0][col], ldsF[kb + 1][col]);
  unsigned u1 = pk2bf(ldsF[kb + 2][col], ldsF[kb + 3][col]);
  unsigned u2 = pk2bf(ldsF[kb + 4][col], ldsF[kb + 5][col]);
  unsigned u3 = pk2bf(ldsF[kb + 6][col], ldsF[kb + 7][col]);
  unsigned short* dst = packW + base + g * (KT * 1024) + t * (KT * 512) + kt * 512 + lane * 8;
  i32x4 v = { (int)u0, (int)u1, (int)u2, (int)u3 };
  *(i32x4*)dst = v;
}

// ======================================================================
// Wave w owns ALL 256 nodes x cols [32w,32w+32). Node->A-row permutation puts
// 16 CONSECUTIVE nodes in each lane's acc regs: node 32nt + 16q + r.
// s~[n] = (h W/3)[n] + bias/3 (bias via acc init) => y[n] = silu(s~[n-1]+s~[n]+s~[n+1]).
// L0 temb-fold: tW = temb @ W0/3 once per wave (9 MFMAs, broadcast A); L0 acc
// init = tW + b0/3; per-node L0 GEMM K=16 (coords+pe, 1 kt).
// 4 subs of 2 tiles, ping-pong acc, kloop interleaved 1:1 with prev-sub epilogue,
// DEPTH-2 A-frag prefetch (covers ~120cy LDS latency; kt&1 static ping-pong).
// Boundary exchange via v_permlane32_swap. h' stores via v_cvt_pk_bf16_f32.
// h[256][256] bf16 in 128KB LDS, 16B-slot XOR swizzle (slot ^= row&31).
// B slice resident in 64 VGPRs (from packW; r8 lesson: direct-W loads spill).
// ======================================================================

// one epilogue PAIR p (values r=2(p&7), +1 of tile t=p>>3); mid-sum shared
template <int ELAYER, bool DF, bool DL>
__device__ __forceinline__ void epi_pair(
    const int p, const f32x16* accEpi, const int q,
    const float recvI0, const float recvI1, const float recvX,
    const float extP, const float extN,
    const int epiSub, unsigned short* __restrict__ hbuf,
    const int* rowAddr, float& psum) {
  const int t = p >> 3, rp = (p & 7) * 2;
  const float mid = accEpi[t][rp] + accEpi[t][rp + 1];
  float prev, next;
  if (rp > 0) prev = accEpi[t][rp - 1];
  else        prev = q ? (t ? recvI1 : recvI0) : (t ? recvX : extP);
  if (rp < 14) next = accEpi[t][rp + 2];
  else         next = q ? (t ? extN : recvX) : (t ? recvI1 : recvI0);
  const float y0 = silu_f(prev + mid);
  const float y1 = silu_f(mid + next);
  const bool c0 = !(DF && t == 0 && rp == 0 && q == 0);
  const bool c1 = !(DL && t == 1 && rp == 14 && q == 1);
  if constexpr (ELAYER == 2) {
    if (c0) psum += y0;
    if (c1) psum += y1;
  } else {
    const unsigned u = pk2bf(y0, y1);
    char* bp = (char*)hbuf + (2 * epiSub + t) * 16384;
    if (c0) *(unsigned short*)(bp + rowAddr[rp])     = (unsigned short)u;
    if (c1) *(unsigned short*)(bp + rowAddr[rp + 1]) = (unsigned short)(u >> 16);
  }
}

// fused block: kloop over 2 tiles of readSub (acc init = bias-ish scalar),
// DEPTH-2 ping-pong A prefetch, interleaved with epilogue pairs of epiSub.
template <int KT, int ELAYER, bool DOEPI, bool DF, bool DL>
__device__ __forceinline__ void fblock(
    unsigned short* __restrict__ hbuf, const int readSub, const int epiSub,
    const bf16x8* Bf, const int q, const int c, const float bias3,
    f32x16* accOut, const f32x16* accEpi,
    const float extP, const float extN,
    const int* rowAddr, float& psum) {
  float recvI0 = 0.f, recvI1 = 0.f, recvX = 0.f;
  if constexpr (DOEPI) {
    recvI0 = xchg32(accEpi[0][0],  accEpi[0][15], q);
    recvI1 = xchg32(accEpi[1][0],  accEpi[1][15], q);
    recvX  = xchg32(accEpi[0][15], accEpi[1][0],  q);
  }
#pragma unroll
  for (int t2 = 0; t2 < 2; ++t2)
#pragma unroll
    for (int j = 0; j < 16; ++j) accOut[t2][j] = bias3;
  const unsigned short* rb = hbuf + readSub * 16384 + c * 256;
  bf16x8 pa[2], pb[2];                           // depth-2 ping-pong prefetch
  pa[0] = *(const bf16x8*)(rb + ((q ^ c) * 8));
  pb[0] = *(const bf16x8*)(rb + ((q ^ c) * 8) + 8192);
  if (KT > 1) {
    pa[1] = *(const bf16x8*)(rb + (((2 + q) ^ c) * 8));
    pb[1] = *(const bf16x8*)(rb + (((2 + q) ^ c) * 8) + 8192);
  }
#pragma unroll
  for (int kt = 0; kt < KT; ++kt) {
    const bf16x8 u0 = pa[kt & 1], u1 = pb[kt & 1];
    if (kt + 2 < KT) {
      const unsigned short* nb = rb + (((2 * (kt + 2) + q) ^ c) * 8);
      pa[kt & 1] = *(const bf16x8*)(nb);
      pb[kt & 1] = *(const bf16x8*)(nb + 8192);
    }
    accOut[0] = __builtin_amdgcn_mfma_f32_32x32x16_bf16(u0, Bf[kt], accOut[0], 0, 0, 0);
    accOut[1] = __builtin_amdgcn_mfma_f32_32x32x16_bf16(u1, Bf[kt], accOut[1], 0, 0, 0);
    if constexpr (DOEPI) {
#pragma unroll
      for (int p = (kt * 16) / KT; p < ((kt + 1) * 16) / KT; ++p)
        epi_pair<ELAYER, DF, DL>(p, accEpi, q, recvI0, recvI1, recvX, extP, extN,
                                 epiSub, hbuf, rowAddr, psum);
    }
  }
}

template <int ELAYER>
__device__ __forceinline__ void epi_only(
    const f32x16* accEpi, const int q, const float extP, const float extN,
    const int epiSub, unsigned short* __restrict__ hbuf,
    const int* rowAddr, float& psum) {
  const float recvI0 = xchg32(accEpi[0][0],  accEpi[0][15], q);
  const float recvI1 = xchg32(accEpi[1][0],  accEpi[1][15], q);
  const float recvX  = xchg32(accEpi[0][15], accEpi[1][0],  q);
#pragma unroll
  for (int p = 0; p < 16; ++p)
    epi_pair<ELAYER, false, false>(p, accEpi, q, recvI0, recvI1, recvX, extP, extN,
                                   epiSub, hbuf, rowAddr, psum);
}

// node 64e+63 (q1 lanes): prev/cur in accEpi[1][14..15], next = new sub's node 64e+64
template <int ELAYER>
__device__ __forceinline__ void defer_last(
    const f32x16* accEpi, const float accNew00, const int epiSub,
    const int q, unsigned short* __restrict__ hbuf,
    const int* rowAddr, float& psum) {
  const float recv = xchg32(0.f, accNew00, q);   // q1 <- s~[64e+64]
  const float y = silu_f(accEpi[1][14] + accEpi[1][15] + recv);
  if (q) {
    if constexpr (ELAYER == 2) psum += y;
    else *(unsigned short*)((char*)hbuf + (2 * epiSub + 1) * 16384 + rowAddr[15]) = f2bf(y);
  }
}

// node 0 (q0 lanes): prev = s~[255], cur/next = saved s~[0], s~[1]
template <int ELAYER>
__device__ __forceinline__ void fix_node0(
    const float s255src, const float sv0, const float sv1,
    const int q, unsigned short* __restrict__ hbuf,
    const int* rowAddr, float& psum) {
  const float recv = xchg32(s255src, 0.f, q);    // q0 <- s~[255]
  const float y = silu_f(recv + sv0 + sv1);
  if (!q) {
    if constexpr (ELAYER == 2) psum += y;
    else *(unsigned short*)((char*)hbuf + rowAddr[0]) = f2bf(y);
  }
}

// ---------------- main fused kernel: 1 block = 1 graph, 8 waves x 32 cols ----------
__global__ __launch_bounds__(512, 1) void poly_kernel(
    const float* __restrict__ x, const float* __restrict__ t,
    const float* __restrict__ tw, const float* __restrict__ tb,
    const unsigned short* __restrict__ packW,
    const float* __restrict__ B0, const float* __restrict__ B1,
    const float* __restrict__ B2, float* __restrict__ out) {
  __shared__ __align__(16) unsigned short hbuf[65536];  // 128 KiB: h[row][256] bf16, swizzled
  __shared__ __align__(16) unsigned short tmpl[160];    // h0 row template (temb + pads)

  const int tid = threadIdx.x;
  const int w = tid >> 6, lane = tid & 63, q = lane >> 5, c = lane & 31;
  const int b = blockIdx.x;

  // ---- fused time MLP: temb = silu(sinemb(t[b]) @ tw + tb) ----
  {
    float* scr = (float*)hbuf;        // reuse h as f32 scratch (overwritten later)
    if (tid < 128) {
      const float tv = t[b];
      const int i = tid & 63;
      const float f = expf(-0.14619588396823767f * (float)i);  // log(1e4)/63
      const float ang = tv * f;
      scr[tid] = (tid < 64) ? sinf(ang) : cosf(ang);
    }
    __syncthreads();
    {
      const int j = tid & 127, p = tid >> 7;   // 4-way k-split over the block
      float a = 0.f;
#pragma unroll 8
      for (int kk = 0; kk < 32; ++kk) a += scr[p * 32 + kk] * tw[(p * 32 + kk) * 128 + j];
      scr[128 + tid] = a;
    }
    __syncthreads();
    if (tid < 128) {
      const float a = tb[tid] + scr[128 + tid] + scr[256 + tid] + scr[384 + tid] + scr[512 + tid];
      tmpl[6 + tid] = f2bf(silu_f(a));
      if (tid < 6)  tmpl[tid] = 0;
      if (tid < 26) tmpl[134 + tid] = 0;   // pad k 134..159 = 0
    }
    __syncthreads();
  }

  // B slices: wave w <-> group g=w>>1, tile t=w&1 (cols 32w..32w+31)
  const unsigned short* pL0 = packW + (w >> 1) * (9 * 1024) + (w & 1) * (9 * 512);
  const unsigned short* pL1 = packW + 36864 + (w >> 1) * (16 * 1024) + (w & 1) * (16 * 512);
  const unsigned short* pL2 = packW + 102400 + (w >> 1) * (16 * 1024) + (w & 1) * (16 * 512);
  bf16x8 Bf[16];
#pragma unroll
  for (int kt = 0; kt < 9; ++kt) Bf[kt] = *(const bf16x8*)(pL0 + kt * 512 + lane * 8);
  const float b30 = B0[w * 32 + c] * 0.33333334f;
  const float b31 = B1[w * 32 + c] * 0.33333334f;
  const float b32 = B2[w * 32 + c] * 0.33333334f;

  // ---- tW fold: node-invariant part of L0 (temb @ W0/3), once per wave ----
  // A rows all = tmpl (zeros in k0..5) -> every C element = tW[col]; take C[0].
  float initL0;
  {
    f32x16 Ct;
#pragma unroll
    for (int j = 0; j < 16; ++j) Ct[j] = 0.f;
#pragma unroll
    for (int kt = 0; kt < 9; ++kt) {
      const bf16x8 at = *(const bf16x8*)(tmpl + kt * 16 + q * 8);
      Ct = __builtin_amdgcn_mfma_f32_32x32x16_bf16(at, Bf[kt], Ct, 0, 0, 0);
    }
    initL0 = Ct[0] + b30;
  }

  // ---- build h0 (features only): slots 0,1 per node = [xy, pe, 0-pad] ----
  {
    const int node = tid >> 1, sl = tid & 1;
    i32x4 d = {0, 0, 0, 0};
    if (sl == 0) {
      const float2 xy = ((const float2*)x)[b * 256 + node];
      const float th = 0.024543692605870074f * (float)node;   // 2*pi/256
      d.x = (int)pk2bf(xy.x, xy.y);
      d.y = (int)pk2bf(sinf(th), cosf(th));
      d.z = (int)pk2bf(sinf(2.f * th), cosf(2.f * th));
    }
    const int m = (node & 3) + 8 * ((node >> 2) & 3) + 4 * ((node >> 4) & 1);
    const int R = (node & ~31) | m;            // permuted LDS row
    *(i32x4*)(hbuf + R * 256 + ((sl ^ m) * 8)) = d;
  }

  // per-lane h'-write byte addresses (row within tile; r compile-time)
  int rowAddr[16];
  const int slotW = 4 * w + (c >> 3), offW = (c & 7) * 2;    // k-index = 32w+c
#pragma unroll
  for (int r = 0; r < 16; ++r) {
    const int row = (r & 3) + 8 * (r >> 2) + 4 * q;
    rowAddr[r] = row * 512 + ((slotW ^ row) * 16) + offW;
  }
  __syncthreads();   // h0 ready

  f32x16 accA[2], accB[2];
  float psum = 0.f, sv0, sv1, extP, extN;

  // ================= L0 (K=16: coords+pe; temb folded into initL0) =================
  fblock<1, 0, false, false, false>(hbuf, 0, 0, Bf, q, c, initL0, accA, accA, 0.f, 0.f, rowAddr, psum);
  sv0 = accA[0][0]; sv1 = accA[0][1];                       // s~[0], s~[1] (q0)
  __syncthreads();
  fblock<1, 0, true, true, true>(hbuf, 1, 0, Bf, q, c, initL0, accB, accA, 0.f, 0.f, rowAddr, psum);
  defer_last<0>(accA, accB[0][0], 0, q, hbuf, rowAddr, psum);       // node 63
  extP = xchg32(accA[1][15], 0.f, q);                               // s~[63] -> q0
  __syncthreads();
  fblock<1, 0, true, false, true>(hbuf, 2, 1, Bf, q, c, initL0, accA, accB, extP, 0.f, rowAddr, psum);
  defer_last<0>(accB, accA[0][0], 1, q, hbuf, rowAddr, psum);       // node 127
  extP = xchg32(accB[1][15], 0.f, q);                               // s~[127]
  __syncthreads();
  fblock<1, 0, true, false, true>(hbuf, 3, 2, Bf, q, c, initL0, accB, accA, extP, 0.f, rowAddr, psum);
  // issue next-layer Bf loads FIRST (VMEM latency hides under fixup VALU + barrier)
#pragma unroll
  for (int kt = 0; kt < 16; ++kt) Bf[kt] = *(const bf16x8*)(pL1 + kt * 512 + lane * 8);
  defer_last<0>(accA, accB[0][0], 2, q, hbuf, rowAddr, psum);       // node 191
  fix_node0<0>(accB[1][15], sv0, sv1, q, hbuf, rowAddr, psum);      // node 0
  extP = xchg32(accA[1][15], 0.f, q);                               // s~[191]
  extN = xchg32(0.f, sv0, q);                                       // s~[0] -> q1
  __syncthreads();

  // ================= L1 =================
  fblock<16, 0, true, false, false>(hbuf, 0, 3, Bf, q, c, b31, accA, accB, extP, extN, rowAddr, psum);
  sv0 = accA[0][0]; sv1 = accA[0][1];
  __syncthreads();
  fblock<16, 1, true, true, true>(hbuf, 1, 0, Bf, q, c, b31, accB, accA, 0.f, 0.f, rowAddr, psum);
  defer_last<1>(accA, accB[0][0], 0, q, hbuf, rowAddr, psum);
  extP = xchg32(accA[1][15], 0.f, q);
  __syncthreads();
  fblock<16, 1, true, false, true>(hbuf, 2, 1, Bf, q, c, b31, accA, accB, extP, 0.f, rowAddr, psum);
  defer_last<1>(accB, accA[0][0], 1, q, hbuf, rowAddr, psum);
  extP = xchg32(accB[1][15], 0.f, q);
  __syncthreads();
  fblock<16, 1, true, false, true>(hbuf, 3, 2, Bf, q, c, b31, accB, accA, extP, 0.f, rowAddr, psum);
#pragma unroll
  for (int kt = 0; kt < 16; ++kt) Bf[kt] = *(const bf16x8*)(pL2 + kt * 512 + lane * 8);
  defer_last<1>(accA, accB[0][0], 2, q, hbuf, rowAddr, psum);
  fix_node0<1>(accB[1][15], sv0, sv1, q, hbuf, rowAddr, psum);
  extP = xchg32(accA[1][15], 0.f, q);
  extN = xchg32(0.f, sv0, q);
  __syncthreads();

  // ================= L2 (pool only; no LDS writes -> fewer barriers) =================
  fblock<16, 1, true, false, false>(hbuf, 0, 3, Bf, q, c, b32, accA, accB, extP, extN, rowAddr, psum);
  sv0 = accA[0][0]; sv1 = accA[0][1];
  __syncthreads();                              // epi(s3,L1) wrote rows 192..255
  fblock<16, 2, true, true, true>(hbuf, 1, 0, Bf, q, c, b32, accB, accA, 0.f, 0.f, rowAddr, psum);
  defer_last<2>(accA, accB[0][0], 0, q, hbuf, rowAddr, psum);
  extP = xchg32(accA[1][15], 0.f, q);
  fblock<16, 2, true, false, true>(hbuf, 2, 1, Bf, q, c, b32, accA, accB, extP, 0.f, rowAddr, psum);
  defer_last<2>(accB, accA[0][0], 1, q, hbuf, rowAddr, psum);
  extP = xchg32(accB[1][15], 0.f, q);
  fblock<16, 2, true, false, true>(hbuf, 3, 2, Bf, q, c, b32, accB, accA, extP, 0.f, rowAddr, psum);
  defer_last<2>(accA, accB[0][0], 2, q, hbuf, rowAddr, psum);
  fix_node0<2>(accB[1][15], sv0, sv1, q, hbuf, rowAddr, psum);
  extP = xchg32(accA[1][15], 0.f, q);
  extN = xchg32(0.f, sv0, q);
  epi_only<2>(accB, q, extP, extN, 3, hbuf, rowAddr, psum);

  const float s2 = psum + xchg32(psum, psum, q);
  if (q == 0) out[b * 256 + w * 32 + c] = s2 * (1.0f / 256.0f);
}

// ---------------- launch ----------------
extern "C" void kernel_launch(void* const* d_in, const int* in_sizes, int n_in,
                              void* d_out, int out_size, void* d_ws, size_t ws_size,
                              hipStream_t stream) {
  const float* x  = (const float*)d_in[0];
  const float* t  = (const float*)d_in[1];
  const float* tw = (const float*)d_in[2];
  const float* tb = (const float*)d_in[3];
  const float* W0 = (const float*)d_in[4];
  const float* b0 = (const float*)d_in[5];
  const float* W1 = (const float*)d_in[6];
  const float* b1 = (const float*)d_in[7];
  const float* W2 = (const float*)d_in[8];
  const float* b2 = (const float*)d_in[9];

  unsigned short* packW = (unsigned short*)d_ws;   // 167936 shorts
  float* out = (float*)d_out;

  pack_kernel<<<41, 512, 0, stream>>>(W0, W1, W2, packW);
  poly_kernel<<<1024, 512, 0, stream>>>(x, t, tw, tb, packW, b0, b1, b2, out);
}

// Round 10
// 174.322 us; speedup vs baseline: 1.4110x; 1.0088x over previous
//
#include <hip/hip_runtime.h>
#include <cstdint>

typedef __attribute__((ext_vector_type(8)))  short bf16x8;   // 8 x bf16 (4 VGPR)
typedef __attribute__((ext_vector_type(16))) float f32x16;   // MFMA 32x32 acc
typedef __attribute__((ext_vector_type(4)))  int   i32x4;

__device__ __forceinline__ unsigned short f2bf(float x) {    // RNE fp32->bf16
  unsigned u = __float_as_uint(x);
  u += 0x7fffu + ((u >> 16) & 1u);
  return (unsigned short)(u >> 16);
}
// packed f32x2 -> bf16x2 in ONE instruction. NOTE: no builtin on gfx950
// (learn_hip m240) -- the __has_builtin guard used all session was dead and
// selected a ~10-op manual fallback. Inline asm emits the real v_cvt_pk.
__device__ __forceinline__ unsigned pk2bf(float lo, float hi) {
  unsigned r;
  asm("v_cvt_pk_bf16_f32 %0, %1, %2" : "=v"(r) : "v"(lo), "v"(hi));
  return r;
}
__device__ __forceinline__ float silu_f(float v) {
  return v * __builtin_amdgcn_rcpf(1.0f + __expf(-v));
}

// half-exchange without the LDS pipe: lanes 0-31 receive A from lane+32,
// lanes 32-63 receive B from lane-32  (== __shfl_xor(q ? A : B, 32)).
__device__ __forceinline__ float xchg32(float A, float B, int q) {
#if defined(__has_builtin)
#if __has_builtin(__builtin_amdgcn_permlane32_swap)
  auto r = __builtin_amdgcn_permlane32_swap(__float_as_uint(A), __float_as_uint(B),
                                            false, false);
  return __uint_as_float(q ? r[0] : r[1]);
#else
  return __shfl_xor(q ? A : B, 32);
#endif
#else
  return __shfl_xor(q ? A : B, 32);
#endif
}

// ---- pack W/3 into MFMA B-frag order via LDS transpose (coalesced R+W).
// 1/3 aggregation factor folded into the weights; bias folded into acc init.
// dest layout: [layer][g(64 cols)][t(32-col tile)][kt][lane][8], K0 padded 134->144.
__global__ void pack_kernel(const float* __restrict__ W0, const float* __restrict__ W1,
                            const float* __restrict__ W2,
                            unsigned short* __restrict__ packW) {
  __shared__ float ldsF[16][257];
  const int s = blockIdx.x, tid = threadIdx.x;
  const float* W; int KT, kmax, base, kt;
  if (s < 9)       { W = W0; KT = 9;  kmax = 134; base = 0;      kt = s; }
  else if (s < 25) { W = W1; KT = 16; kmax = 256; base = 36864;  kt = s - 9; }
  else             { W = W2; KT = 16; kmax = 256; base = 102400; kt = s - 25; }
  const int k0 = kt * 16;
#pragma unroll
  for (int i = 0; i < 8; ++i) {                 // 512 thr x 8 = 16 x 256 floats
    const int idx = i * 512 + tid;
    const int kl = idx >> 8, col = idx & 255;
    const int kg = k0 + kl;
    ldsF[kl][col] = (kg < kmax) ? W[kg * 256 + col] * 0.33333334f : 0.0f;
  }
  __syncthreads();
  const int g = tid >> 7, t = (tid >> 6) & 1, lane = tid & 63;
  const int col = g * 64 + t * 32 + (lane & 31);
  const int kb = 8 * (lane >> 5);
  unsigned u0 = pk2bf(ldsF[kb + 0][col], ldsF[kb + 1][col]);
  unsigned u1 = pk2bf(ldsF[kb + 2][col], ldsF[kb + 3][col]);
  unsigned u2 = pk2bf(ldsF[kb + 4][col], ldsF[kb + 5][col]);
  unsigned u3 = pk2bf(ldsF[kb + 6][col], ldsF[kb + 7][col]);
  unsigned short* dst = packW + base + g * (KT * 1024) + t * (KT * 512) + kt * 512 + lane * 8;
  i32x4 v = { (int)u0, (int)u1, (int)u2, (int)u3 };
  *(i32x4*)dst = v;
}

// ======================================================================
// Wave w owns ALL 256 nodes x cols [32w,32w+32). Node->A-row permutation puts
// 16 CONSECUTIVE nodes in each lane's acc regs: node 32nt + 16q + r.
// s~[n] = (h W/3)[n] + bias/3 (bias via acc init) => y[n] = silu(s~[n-1]+s~[n]+s~[n+1]).
// L0 temb-fold: tW = temb @ W0/3 once per wave (9 MFMAs, broadcast A); L0 acc
// init = tW + b0/3; per-node L0 GEMM K=16 (coords+pe, 1 kt).
// 4 subs of 2 tiles, ping-pong acc, kloop interleaved 1:1 with prev-sub epilogue,
// depth-1 A-frag prefetch (depth-2 measured neutral, r9). Boundary exchange via
// v_permlane32_swap. h' stores via v_cvt_pk_bf16_f32 (inline asm).
// h[256][256] bf16 in 128KB LDS, 16B-slot XOR swizzle (slot ^= row&31).
// B slice resident in 64 VGPRs (from packW; r8 lesson: direct-W loads spill).
// ======================================================================

// one epilogue PAIR p (values r=2(p&7), +1 of tile t=p>>3); mid-sum shared
template <int ELAYER, bool DF, bool DL>
__device__ __forceinline__ void epi_pair(
    const int p, const f32x16* accEpi, const int q,
    const float recvI0, const float recvI1, const float recvX,
    const float extP, const float extN,
    const int epiSub, unsigned short* __restrict__ hbuf,
    const int* rowAddr, float& psum) {
  const int t = p >> 3, rp = (p & 7) * 2;
  const float mid = accEpi[t][rp] + accEpi[t][rp + 1];
  float prev, next;
  if (rp > 0) prev = accEpi[t][rp - 1];
  else        prev = q ? (t ? recvI1 : recvI0) : (t ? recvX : extP);
  if (rp < 14) next = accEpi[t][rp + 2];
  else         next = q ? (t ? extN : recvX) : (t ? recvI1 : recvI0);
  const float y0 = silu_f(prev + mid);
  const float y1 = silu_f(mid + next);
  const bool c0 = !(DF && t == 0 && rp == 0 && q == 0);
  const bool c1 = !(DL && t == 1 && rp == 14 && q == 1);
  if constexpr (ELAYER == 2) {
    if (c0) psum += y0;
    if (c1) psum += y1;
  } else {
    const unsigned u = pk2bf(y0, y1);
    char* bp = (char*)hbuf + (2 * epiSub + t) * 16384;
    if (c0) *(unsigned short*)(bp + rowAddr[rp])     = (unsigned short)u;
    if (c1) *(unsigned short*)(bp + rowAddr[rp + 1]) = (unsigned short)(u >> 16);
  }
}

// fused block: kloop over 2 tiles of readSub (acc init = bias-ish scalar),
// depth-1 A prefetch, interleaved with epilogue pairs of epiSub (prev sub).
template <int KT, int ELAYER, bool DOEPI, bool DF, bool DL>
__device__ __forceinline__ void fblock(
    unsigned short* __restrict__ hbuf, const int readSub, const int epiSub,
    const bf16x8* Bf, const int q, const int c, const float bias3,
    f32x16* accOut, const f32x16* accEpi,
    const float extP, const float extN,
    const int* rowAddr, float& psum) {
  float recvI0 = 0.f, recvI1 = 0.f, recvX = 0.f;
  if constexpr (DOEPI) {
    recvI0 = xchg32(accEpi[0][0],  accEpi[0][15], q);
    recvI1 = xchg32(accEpi[1][0],  accEpi[1][15], q);
    recvX  = xchg32(accEpi[0][15], accEpi[1][0],  q);
  }
#pragma unroll
  for (int t2 = 0; t2 < 2; ++t2)
#pragma unroll
    for (int j = 0; j < 16; ++j) accOut[t2][j] = bias3;
  const unsigned short* rb = hbuf + readSub * 16384 + c * 256;
  bf16x8 a0 = *(const bf16x8*)(rb + ((q ^ c) * 8));
  bf16x8 a1 = *(const bf16x8*)(rb + ((q ^ c) * 8) + 8192);
#pragma unroll
  for (int kt = 0; kt < KT; ++kt) {
    const bf16x8 u0 = a0, u1 = a1;
    if (kt + 1 < KT) {                          // depth-1 prefetch
      const unsigned short* nb = rb + (((2 * (kt + 1) + q) ^ c) * 8);
      a0 = *(const bf16x8*)(nb);
      a1 = *(const bf16x8*)(nb + 8192);
    }
    accOut[0] = __builtin_amdgcn_mfma_f32_32x32x16_bf16(u0, Bf[kt], accOut[0], 0, 0, 0);
    accOut[1] = __builtin_amdgcn_mfma_f32_32x32x16_bf16(u1, Bf[kt], accOut[1], 0, 0, 0);
    if constexpr (DOEPI) {
#pragma unroll
      for (int p = (kt * 16) / KT; p < ((kt + 1) * 16) / KT; ++p)
        epi_pair<ELAYER, DF, DL>(p, accEpi, q, recvI0, recvI1, recvX, extP, extN,
                                 epiSub, hbuf, rowAddr, psum);
    }
  }
}

template <int ELAYER>
__device__ __forceinline__ void epi_only(
    const f32x16* accEpi, const int q, const float extP, const float extN,
    const int epiSub, unsigned short* __restrict__ hbuf,
    const int* rowAddr, float& psum) {
  const float recvI0 = xchg32(accEpi[0][0],  accEpi[0][15], q);
  const float recvI1 = xchg32(accEpi[1][0],  accEpi[1][15], q);
  const float recvX  = xchg32(accEpi[0][15], accEpi[1][0],  q);
#pragma unroll
  for (int p = 0; p < 16; ++p)
    epi_pair<ELAYER, false, false>(p, accEpi, q, recvI0, recvI1, recvX, extP, extN,
                                   epiSub, hbuf, rowAddr, psum);
}

// node 64e+63 (q1 lanes): prev/cur in accEpi[1][14..15], next = new sub's node 64e+64
template <int ELAYER>
__device__ __forceinline__ void defer_last(
    const f32x16* accEpi, const float accNew00, const int epiSub,
    const int q, unsigned short* __restrict__ hbuf,
    const int* rowAddr, float& psum) {
  const float recv = xchg32(0.f, accNew00, q);   // q1 <- s~[64e+64]
  const float y = silu_f(accEpi[1][14] + accEpi[1][15] + recv);
  if (q) {
    if constexpr (ELAYER == 2) psum += y;
    else *(unsigned short*)((char*)hbuf + (2 * epiSub + 1) * 16384 + rowAddr[15]) = f2bf(y);
  }
}

// node 0 (q0 lanes): prev = s~[255], cur/next = saved s~[0], s~[1]
template <int ELAYER>
__device__ __forceinline__ void fix_node0(
    const float s255src, const float sv0, const float sv1,
    const int q, unsigned short* __restrict__ hbuf,
    const int* rowAddr, float& psum) {
  const float recv = xchg32(s255src, 0.f, q);    // q0 <- s~[255]
  const float y = silu_f(recv + sv0 + sv1);
  if (!q) {
    if constexpr (ELAYER == 2) psum += y;
    else *(unsigned short*)((char*)hbuf + rowAddr[0]) = f2bf(y);
  }
}

// ---------------- main fused kernel: 1 block = 1 graph, 8 waves x 32 cols ----------
__global__ __launch_bounds__(512, 1) void poly_kernel(
    const float* __restrict__ x, const float* __restrict__ t,
    const float* __restrict__ tw, const float* __restrict__ tb,
    const unsigned short* __restrict__ packW,
    const float* __restrict__ B0, const float* __restrict__ B1,
    const float* __restrict__ B2, float* __restrict__ out) {
  __shared__ __align__(16) unsigned short hbuf[65536];  // 128 KiB: h[row][256] bf16, swizzled
  __shared__ __align__(16) unsigned short tmpl[160];    // h0 row template (temb + pads)

  const int tid = threadIdx.x;
  const int w = tid >> 6, lane = tid & 63, q = lane >> 5, c = lane & 31;
  const int b = blockIdx.x;

  // ---- fused time MLP: temb = silu(sinemb(t[b]) @ tw + tb) ----
  {
    float* scr = (float*)hbuf;        // reuse h as f32 scratch (overwritten later)
    if (tid < 128) {
      const float tv = t[b];
      const int i = tid & 63;
      const float f = expf(-0.14619588396823767f * (float)i);  // log(1e4)/63
      const float ang = tv * f;
      scr[tid] = (tid < 64) ? sinf(ang) : cosf(ang);
    }
    __syncthreads();
    {
      const int j = tid & 127, p = tid >> 7;   // 4-way k-split over the block
      float a = 0.f;
#pragma unroll 8
      for (int kk = 0; kk < 32; ++kk) a += scr[p * 32 + kk] * tw[(p * 32 + kk) * 128 + j];
      scr[128 + tid] = a;
    }
    __syncthreads();
    if (tid < 128) {
      const float a = tb[tid] + scr[128 + tid] + scr[256 + tid] + scr[384 + tid] + scr[512 + tid];
      tmpl[6 + tid] = f2bf(silu_f(a));
      if (tid < 6)  tmpl[tid] = 0;
      if (tid < 26) tmpl[134 + tid] = 0;   // pad k 134..159 = 0
    }
    __syncthreads();
  }

  // B slices: wave w <-> group g=w>>1, tile t=w&1 (cols 32w..32w+31)
  const unsigned short* pL0 = packW + (w >> 1) * (9 * 1024) + (w & 1) * (9 * 512);
  const unsigned short* pL1 = packW + 36864 + (w >> 1) * (16 * 1024) + (w & 1) * (16 * 512);
  const unsigned short* pL2 = packW + 102400 + (w >> 1) * (16 * 1024) + (w & 1) * (16 * 512);
  bf16x8 Bf[16];
#pragma unroll
  for (int kt = 0; kt < 9; ++kt) Bf[kt] = *(const bf16x8*)(pL0 + kt * 512 + lane * 8);
  const float b30 = B0[w * 32 + c] * 0.33333334f;
  const float b31 = B1[w * 32 + c] * 0.33333334f;
  const float b32 = B2[w * 32 + c] * 0.33333334f;

  // ---- tW fold: node-invariant part of L0 (temb @ W0/3), once per wave ----
  // A rows all = tmpl (zeros in k0..5) -> every C element = tW[col]; take C[0].
  float initL0;
  {
    f32x16 Ct;
#pragma unroll
    for (int j = 0; j < 16; ++j) Ct[j] = 0.f;
#pragma unroll
    for (int kt = 0; kt < 9; ++kt) {
      const bf16x8 at = *(const bf16x8*)(tmpl + kt * 16 + q * 8);
      Ct = __builtin_amdgcn_mfma_f32_32x32x16_bf16(at, Bf[kt], Ct, 0, 0, 0);
    }
    initL0 = Ct[0] + b30;
  }

  // ---- build h0 (features only): slots 0,1 per node = [xy, pe, 0-pad] ----
  {
    const int node = tid >> 1, sl = tid & 1;
    i32x4 d = {0, 0, 0, 0};
    if (sl == 0) {
      const float2 xy = ((const float2*)x)[b * 256 + node];
      const float th = 0.024543692605870074f * (float)node;   // 2*pi/256
      d.x = (int)pk2bf(xy.x, xy.y);
      d.y = (int)pk2bf(sinf(th), cosf(th));
      d.z = (int)pk2bf(sinf(2.f * th), cosf(2.f * th));
    }
    const int m = (node & 3) + 8 * ((node >> 2) & 3) + 4 * ((node >> 4) & 1);
    const int R = (node & ~31) | m;            // permuted LDS row
    *(i32x4*)(hbuf + R * 256 + ((sl ^ m) * 8)) = d;
  }

  // per-lane h'-write byte addresses (row within tile; r compile-time)
  int rowAddr[16];
  const int slotW = 4 * w + (c >> 3), offW = (c & 7) * 2;    // k-index = 32w+c
#pragma unroll
  for (int r = 0; r < 16; ++r) {
    const int row = (r & 3) + 8 * (r >> 2) + 4 * q;
    rowAddr[r] = row * 512 + ((slotW ^ row) * 16) + offW;
  }
  __syncthreads();   // h0 ready

  f32x16 accA[2], accB[2];
  float psum = 0.f, sv0, sv1, extP, extN;

  // ================= L0 (K=16: coords+pe; temb folded into initL0) =================
  fblock<1, 0, false, false, false>(hbuf, 0, 0, Bf, q, c, initL0, accA, accA, 0.f, 0.f, rowAddr, psum);
  sv0 = accA[0][0]; sv1 = accA[0][1];                       // s~[0], s~[1] (q0)
  __syncthreads();
  fblock<1, 0, true, true, true>(hbuf, 1, 0, Bf, q, c, initL0, accB, accA, 0.f, 0.f, rowAddr, psum);
  defer_last<0>(accA, accB[0][0], 0, q, hbuf, rowAddr, psum);       // node 63
  extP = xchg32(accA[1][15], 0.f, q);                               // s~[63] -> q0
  __syncthreads();
  fblock<1, 0, true, false, true>(hbuf, 2, 1, Bf, q, c, initL0, accA, accB, extP, 0.f, rowAddr, psum);
  defer_last<0>(accB, accA[0][0], 1, q, hbuf, rowAddr, psum);       // node 127
  extP = xchg32(accB[1][15], 0.f, q);                               // s~[127]
  __syncthreads();
  fblock<1, 0, true, false, true>(hbuf, 3, 2, Bf, q, c, initL0, accB, accA, extP, 0.f, rowAddr, psum);
  // issue next-layer Bf loads FIRST (VMEM latency hides under fixup VALU + barrier)
#pragma unroll
  for (int kt = 0; kt < 16; ++kt) Bf[kt] = *(const bf16x8*)(pL1 + kt * 512 + lane * 8);
  defer_last<0>(accA, accB[0][0], 2, q, hbuf, rowAddr, psum);       // node 191
  fix_node0<0>(accB[1][15], sv0, sv1, q, hbuf, rowAddr, psum);      // node 0
  extP = xchg32(accA[1][15], 0.f, q);                               // s~[191]
  extN = xchg32(0.f, sv0, q);                                       // s~[0] -> q1
  __syncthreads();

  // ================= L1 =================
  fblock<16, 0, true, false, false>(hbuf, 0, 3, Bf, q, c, b31, accA, accB, extP, extN, rowAddr, psum);
  sv0 = accA[0][0]; sv1 = accA[0][1];
  __syncthreads();
  fblock<16, 1, true, true, true>(hbuf, 1, 0, Bf, q, c, b31, accB, accA, 0.f, 0.f, rowAddr, psum);
  defer_last<1>(accA, accB[0][0], 0, q, hbuf, rowAddr, psum);
  extP = xchg32(accA[1][15], 0.f, q);
  __syncthreads();
  fblock<16, 1, true, false, true>(hbuf, 2, 1, Bf, q, c, b31, accA, accB, extP, 0.f, rowAddr, psum);
  defer_last<1>(accB, accA[0][0], 1, q, hbuf, rowAddr, psum);
  extP = xchg32(accB[1][15], 0.f, q);
  __syncthreads();
  fblock<16, 1, true, false, true>(hbuf, 3, 2, Bf, q, c, b31, accB, accA, extP, 0.f, rowAddr, psum);
#pragma unroll
  for (int kt = 0; kt < 16; ++kt) Bf[kt] = *(const bf16x8*)(pL2 + kt * 512 + lane * 8);
  defer_last<1>(accA, accB[0][0], 2, q, hbuf, rowAddr, psum);
  fix_node0<1>(accB[1][15], sv0, sv1, q, hbuf, rowAddr, psum);
  extP = xchg32(accA[1][15], 0.f, q);
  extN = xchg32(0.f, sv0, q);
  __syncthreads();

  // ================= L2 (pool only; no LDS writes -> fewer barriers) =================
  fblock<16, 1, true, false, false>(hbuf, 0, 3, Bf, q, c, b32, accA, accB, extP, extN, rowAddr, psum);
  sv0 = accA[0][0]; sv1 = accA[0][1];
  __syncthreads();                              // epi(s3,L1) wrote rows 192..255
  fblock<16, 2, true, true, true>(hbuf, 1, 0, Bf, q, c, b32, accB, accA, 0.f, 0.f, rowAddr, psum);
  defer_last<2>(accA, accB[0][0], 0, q, hbuf, rowAddr, psum);
  extP = xchg32(accA[1][15], 0.f, q);
  fblock<16, 2, true, false, true>(hbuf, 2, 1, Bf, q, c, b32, accA, accB, extP, 0.f, rowAddr, psum);
  defer_last<2>(accB, accA[0][0], 1, q, hbuf, rowAddr, psum);
  extP = xchg32(accB[1][15], 0.f, q);
  fblock<16, 2, true, false, true>(hbuf, 3, 2, Bf, q, c, b32, accB, accA, extP, 0.f, rowAddr, psum);
  defer_last<2>(accA, accB[0][0], 2, q, hbuf, rowAddr, psum);
  fix_node0<2>(accB[1][15], sv0, sv1, q, hbuf, rowAddr, psum);
  extP = xchg32(accA[1][15], 0.f, q);
  extN = xchg32(0.f, sv0, q);
  epi_only<2>(accB, q, extP, extN, 3, hbuf, rowAddr, psum);

  const float s2 = psum + xchg32(psum, psum, q);
  if (q == 0) out[b * 256 + w * 32 + c] = s2 * (1.0f / 256.0f);
}

// ---------------- launch ----------------
extern "C" void kernel_launch(void* const* d_in, const int* in_sizes, int n_in,
                              void* d_out, int out_size, void* d_ws, size_t ws_size,
                              hipStream_t stream) {
  const float* x  = (const float*)d_in[0];
  const float* t  = (const float*)d_in[1];
  const float* tw = (const float*)d_in[2];
  const float* tb = (const float*)d_in[3];
  const float* W0 = (const float*)d_in[4];
  const float* b0 = (const float*)d_in[5];
  const float* W1 = (const float*)d_in[6];
  const float* b1 = (const float*)d_in[7];
  const float* W2 = (const float*)d_in[8];
  const float* b2 = (const float*)d_in[9];

  unsigned short* packW = (unsigned short*)d_ws;   // 167936 shorts
  float* out = (float*)d_out;

  pack_kernel<<<41, 512, 0, stream>>>(W0, W1, W2, packW);
  poly_kernel<<<1024, 512, 0, stream>>>(x, t, tw, tb, packW, b0, b1, b2, out);
}